// Round 1
// baseline (255.711 us; speedup 1.0000x reference)
//
#include <hip/hip_runtime.h>

// Problem constants (match reference)
constexpr int B = 1024, N = 100, C = 256, K = 3;
constexpr int ROWS = B * N;            // 102400
constexpr int WAVES_PER_BLOCK = 4;     // 256 threads / 64-lane waves
constexpr int BLOCKS = ROWS / WAVES_PER_BLOCK;  // 25600, exact
constexpr float LN_EPS = 1e-5f;

__global__ __launch_bounds__(256) void dydwconv_ln_kernel(
    const float* __restrict__ query,   // [B,N,C]
    const float* __restrict__ value,   // [B,N,C]
    const float* __restrict__ Ww,      // [K,C]
    const float* __restrict__ bw,      // [K]
    const float* __restrict__ gamma,   // [C]
    const float* __restrict__ beta,    // [C]
    float* __restrict__ out)           // [B,N,C]
{
    __shared__ float sW[K * C];        // 3 KB
    __shared__ float sGamma[C];
    __shared__ float sBeta[C];
    __shared__ float sBw[K];

    const int t = threadIdx.x;
    // Stage small read-mostly tensors into LDS (once per block)
    sW[t]         = Ww[t];
    sW[t + C]     = Ww[t + C];
    sW[t + 2 * C] = Ww[t + 2 * C];
    sGamma[t] = gamma[t];
    sBeta[t]  = beta[t];
    if (t < K) sBw[t] = bw[t];
    __syncthreads();

    const int wave = t >> 6;
    const int lane = t & 63;
    const int row  = blockIdx.x * WAVES_PER_BLOCK + wave;  // < ROWS always (exact division)

    const size_t base = (size_t)row * C + lane * 4;
    const float4 q4 = *(const float4*)(query + base);
    const float4 v4 = *(const float4*)(value + base);

    const int c0 = lane * 4;
    // Partial dots for the 3 dynamic kernel taps
    float p0 = q4.x * sW[c0]         + q4.y * sW[c0 + 1]         + q4.z * sW[c0 + 2]         + q4.w * sW[c0 + 3];
    float p1 = q4.x * sW[C + c0]     + q4.y * sW[C + c0 + 1]     + q4.z * sW[C + c0 + 2]     + q4.w * sW[C + c0 + 3];
    float p2 = q4.x * sW[2*C + c0]   + q4.y * sW[2*C + c0 + 1]   + q4.z * sW[2*C + c0 + 2]   + q4.w * sW[2*C + c0 + 3];

    #pragma unroll
    for (int off = 32; off > 0; off >>= 1) {
        p0 += __shfl_xor(p0, off);
        p1 += __shfl_xor(p1, off);
        p2 += __shfl_xor(p2, off);
    }
    const float w0 = p0 + sBw[0];
    const float w1 = p1 + sBw[1];
    const float w2 = p2 + sBw[2];

    // Halo exchange for the K=3 conv along channels (zero padding at ends)
    float vleft  = __shfl_up(v4.w, 1);    // value[c0-1] (prev lane's .w)
    float vright = __shfl_down(v4.x, 1);  // value[c0+4] (next lane's .x)
    if (lane == 0)  vleft  = 0.0f;
    if (lane == 63) vright = 0.0f;

    // out[c] = v[c-1]*w0 + v[c]*w1 + v[c+1]*w2  (cross-correlation, pad=1)
    const float o0 = vleft * w0 + v4.x * w1 + v4.y * w2;
    const float o1 = v4.x  * w0 + v4.y * w1 + v4.z * w2;
    const float o2 = v4.y  * w0 + v4.z * w1 + v4.w * w2;
    const float o3 = v4.z  * w0 + v4.w * w1 + vright * w2;

    // LayerNorm over C
    float s  = o0 + o1 + o2 + o3;
    float ss = o0 * o0 + o1 * o1 + o2 * o2 + o3 * o3;
    #pragma unroll
    for (int off = 32; off > 0; off >>= 1) {
        s  += __shfl_xor(s, off);
        ss += __shfl_xor(ss, off);
    }
    const float mu  = s * (1.0f / C);
    const float var = ss * (1.0f / C) - mu * mu;
    const float inv = rsqrtf(var + LN_EPS);

    float4 r;
    r.x = (o0 - mu) * inv * sGamma[c0]     + sBeta[c0];
    r.y = (o1 - mu) * inv * sGamma[c0 + 1] + sBeta[c0 + 1];
    r.z = (o2 - mu) * inv * sGamma[c0 + 2] + sBeta[c0 + 2];
    r.w = (o3 - mu) * inv * sGamma[c0 + 3] + sBeta[c0 + 3];
    *(float4*)(out + base) = r;
}

extern "C" void kernel_launch(void* const* d_in, const int* in_sizes, int n_in,
                              void* d_out, int out_size, void* d_ws, size_t ws_size,
                              hipStream_t stream) {
    const float* query = (const float*)d_in[0];
    const float* value = (const float*)d_in[1];
    const float* Ww    = (const float*)d_in[2];
    const float* bw    = (const float*)d_in[3];
    const float* gamma = (const float*)d_in[4];
    const float* beta  = (const float*)d_in[5];
    float* out = (float*)d_out;

    dydwconv_ln_kernel<<<BLOCKS, 256, 0, stream>>>(query, value, Ww, bw, gamma, beta, out);
}